// Round 1
// baseline (38.598 us; speedup 1.0000x reference)
//
#include <hip/hip_runtime.h>

#define BB 4096
#define NN 64
#define DD 128

// ---------------- Kernel A ----------------
// One block per b (4096 blocks, 256 threads).
// Computes v[b][d] = sum_n softmax_n(nbr_n . Ww_b)[n] * nbr[b][n][d]
// (uniform 1/N when sum(concept[b]) == 0).
__global__ __launch_bounds__(256) void kA(
    const float* __restrict__ conc,
    const float* __restrict__ nbr,
    const float* __restrict__ Ww,
    float* __restrict__ vout)
{
    const int b = blockIdx.x;
    const int t = threadIdx.x;

    __shared__ __align__(16) float tile[NN * 132];   // padded row stride 132
    __shared__ float wsm[NN];
    __shared__ float logits[NN];
    __shared__ float vtmp[DD];

    const float4* nb4 = reinterpret_cast<const float4*>(nbr + (size_t)b * NN * DD);
    const int cg = t & 31;          // column-group: words cg*4 .. cg*4+3
    const int g  = t >> 5;          // half-wave group 0..7
    const float4 wb = reinterpret_cast<const float4*>(Ww + DD)[cg];  // Ww_b slice

    // Stage neighbor tile + logit partials in one pass over global.
    float p[8];
#pragma unroll
    for (int i = 0; i < 8; ++i) {
        float4 val = nb4[t + 256 * i];
        int n = g + 8 * i;
        *reinterpret_cast<float4*>(&tile[n * 132 + cg * 4]) = val;
        p[i] = val.x * wb.x + val.y * wb.y + val.z * wb.z + val.w * wb.w;
    }
    // Reduce each partial within its 32-lane half-wave (group g).
#pragma unroll
    for (int i = 0; i < 8; ++i) {
        float x = p[i];
        x += __shfl_xor(x, 1);
        x += __shfl_xor(x, 2);
        x += __shfl_xor(x, 4);
        x += __shfl_xor(x, 8);
        x += __shfl_xor(x, 16);
        p[i] = x;
    }
    if (cg == 0) {
#pragma unroll
        for (int i = 0; i < 8; ++i) logits[g + 8 * i] = p[i];
    }

    // Concept row (for mask_c) loaded by wave 0.
    float cpart = 0.0f;
    if (t < 64) {
        const float* crow = conc + (size_t)b * DD;
        cpart = crow[t] + crow[t + 64];
    }
    __syncthreads();

    // Softmax over 64 logits: wave 0 only.
    if (t < 64) {
        float sc = cpart;
        sc += __shfl_xor(sc, 1);
        sc += __shfl_xor(sc, 2);
        sc += __shfl_xor(sc, 4);
        sc += __shfl_xor(sc, 8);
        sc += __shfl_xor(sc, 16);
        sc += __shfl_xor(sc, 32);

        float l = logits[t];
        float m = l;
        m = fmaxf(m, __shfl_xor(m, 1));
        m = fmaxf(m, __shfl_xor(m, 2));
        m = fmaxf(m, __shfl_xor(m, 4));
        m = fmaxf(m, __shfl_xor(m, 8));
        m = fmaxf(m, __shfl_xor(m, 16));
        m = fmaxf(m, __shfl_xor(m, 32));
        float e = __expf(l - m);
        float s = e;
        s += __shfl_xor(s, 1);
        s += __shfl_xor(s, 2);
        s += __shfl_xor(s, 4);
        s += __shfl_xor(s, 8);
        s += __shfl_xor(s, 16);
        s += __shfl_xor(s, 32);
        wsm[t] = (sc != 0.0f) ? (e / s) : (1.0f / 64.0f);
    }
    __syncthreads();

    // Weighted sum over rows: thread t -> column d, half h of the 64 rows.
    const int d = t & 127;
    const int h = t >> 7;
    float acc = 0.0f;
#pragma unroll
    for (int j = 0; j < 32; ++j) {
        int row = h * 32 + j;
        acc += wsm[row] * tile[row * 132 + d];
    }
    if (h == 1) vtmp[d] = acc;
    __syncthreads();
    if (h == 0) vout[(size_t)b * DD + d] = acc + vtmp[d];
}

// ---------------- Kernel B ----------------
// y = mask_s/2 * ( [65*stu ; 64*conc+v] @ Ws + 65*bs )
// Grid 256 blocks x 256 threads; 16 rows of B per block; K=256 in 4 chunks.
__global__ __launch_bounds__(256) void kB(
    const float* __restrict__ stu,
    const float* __restrict__ conc,
    const float* vin,                    // may alias y
    const float* __restrict__ Ws,
    const float* __restrict__ bs,
    float* y)
{
    const int t  = threadIdx.x;
    const int r0 = blockIdx.x * 16;

    __shared__ __align__(16) float uL[16 * 256];
    __shared__ __align__(16) float wL[64 * 132];
    __shared__ float psum[256];
    __shared__ float maskhalf[16];

    // Stage u = [65*stu ; 64*conc + v]
    {
        const float4* stu4 = reinterpret_cast<const float4*>(stu  + (size_t)r0 * DD);
        const float4* con4 = reinterpret_cast<const float4*>(conc + (size_t)r0 * DD);
        const float4* v4   = reinterpret_cast<const float4*>(vin  + (size_t)r0 * DD);
#pragma unroll
        for (int i = 0; i < 4; ++i) {
            int flat = t + 256 * i;      // 0..1023 float4 slots
            int r    = flat >> 6;        // row 0..15
            int kq   = flat & 63;        // float4 index within the 256-wide row
            float4 o;
            if (kq < 32) {
                float4 sv = stu4[r * 32 + kq];
                o.x = 65.0f * sv.x; o.y = 65.0f * sv.y;
                o.z = 65.0f * sv.z; o.w = 65.0f * sv.w;
            } else {
                float4 cv = con4[r * 32 + (kq - 32)];
                float4 vv = v4  [r * 32 + (kq - 32)];
                o.x = 64.0f * cv.x + vv.x; o.y = 64.0f * cv.y + vv.y;
                o.z = 64.0f * cv.z + vv.z; o.w = 64.0f * cv.w + vv.w;
            }
            *reinterpret_cast<float4*>(&uL[r * 256 + kq * 4]) = o;
        }
    }
    // Row-sum partials of stu (for mask_s): thread t -> row t>>4, 8 elems.
    {
        int r   = t >> 4;
        int seg = t & 15;
        const float* srow = stu + (size_t)(r0 + r) * DD + seg * 8;
        float s = 0.0f;
#pragma unroll
        for (int j = 0; j < 8; ++j) s += srow[j];
        psum[t] = s;
    }
    __syncthreads();
    if (t < 16) {
        float s = 0.0f;
#pragma unroll
        for (int j = 0; j < 16; ++j) s += psum[t * 16 + j];
        maskhalf[t] = (s != 0.0f) ? 0.5f : 0.0f;
    }

    const int ccg = t & 31;   // cols ccg*4 .. +3
    const int rg  = t >> 5;   // rows rg*2, rg*2+1
    float a00 = 0.f, a01 = 0.f, a02 = 0.f, a03 = 0.f;
    float a10 = 0.f, a11 = 0.f, a12 = 0.f, a13 = 0.f;

    const float4* Ws4 = reinterpret_cast<const float4*>(Ws);  // 256 x 32 float4
    for (int kc = 0; kc < 4; ++kc) {
        // Stage W chunk (rows kc*64 .. +63) into wL, padded stride 132.
#pragma unroll
        for (int i = 0; i < 8; ++i) {
            int flat = t + 256 * i;      // 0..2047
            int kk   = flat >> 5;
            int c4   = flat & 31;
            float4 wv = Ws4[(size_t)kc * 2048 + flat];
            *reinterpret_cast<float4*>(&wL[kk * 132 + c4 * 4]) = wv;
            (void)kk; (void)c4;
        }
        __syncthreads();
#pragma unroll
        for (int kk = 0; kk < 64; ++kk) {
            float u0 = uL[(rg * 2 + 0) * 256 + kc * 64 + kk];
            float u1 = uL[(rg * 2 + 1) * 256 + kc * 64 + kk];
            float4 wv = *reinterpret_cast<const float4*>(&wL[kk * 132 + ccg * 4]);
            a00 += u0 * wv.x; a01 += u0 * wv.y; a02 += u0 * wv.z; a03 += u0 * wv.w;
            a10 += u1 * wv.x; a11 += u1 * wv.y; a12 += u1 * wv.z; a13 += u1 * wv.w;
        }
        __syncthreads();
    }

    // Epilogue: + 65*bs, * mask_s * 0.5
    float4 bv = reinterpret_cast<const float4*>(bs)[ccg];
    float m0 = maskhalf[rg * 2 + 0];
    float m1 = maskhalf[rg * 2 + 1];
    float4 o0, o1;
    o0.x = (a00 + 65.0f * bv.x) * m0; o0.y = (a01 + 65.0f * bv.y) * m0;
    o0.z = (a02 + 65.0f * bv.z) * m0; o0.w = (a03 + 65.0f * bv.w) * m0;
    o1.x = (a10 + 65.0f * bv.x) * m1; o1.y = (a11 + 65.0f * bv.y) * m1;
    o1.z = (a12 + 65.0f * bv.z) * m1; o1.w = (a13 + 65.0f * bv.w) * m1;
    float4* yrow0 = reinterpret_cast<float4*>(y + (size_t)(r0 + rg * 2 + 0) * DD);
    float4* yrow1 = reinterpret_cast<float4*>(y + (size_t)(r0 + rg * 2 + 1) * DD);
    yrow0[ccg] = o0;
    yrow1[ccg] = o1;
}

extern "C" void kernel_launch(void* const* d_in, const int* in_sizes, int n_in,
                              void* d_out, int out_size, void* d_ws, size_t ws_size,
                              hipStream_t stream) {
    const float* stu  = (const float*)d_in[0];
    const float* conc = (const float*)d_in[1];
    const float* nbr  = (const float*)d_in[2];
    const float* Ws   = (const float*)d_in[3];
    const float* bs   = (const float*)d_in[4];
    const float* Ww   = (const float*)d_in[5];
    float* y = (float*)d_out;

    // v scratch: prefer workspace; d_out is safe too (kB reads v rows into LDS
    // before writing y rows, and blocks own disjoint rows).
    float* v = (ws_size >= (size_t)BB * DD * sizeof(float)) ? (float*)d_ws : y;

    kA<<<BB, 256, 0, stream>>>(conc, nbr, Ww, v);
    kB<<<BB / 16, 256, 0, stream>>>(stu, conc, v, Ws, bs, y);
}

// Round 2
// 33.073 us; speedup vs baseline: 1.1670x; 1.1670x over previous
//
#include <hip/hip_runtime.h>

#define BB 4096
#define NN 64
#define DD 128
#define G  4

// Fused: per block, G=4 rows of b.
// Phase 1 (per row): v[b] = sum_n softmax_n(nbr_n . Ww_b) * nbr_n, neighbor
//   tile held in registers; builds u = [65*stu ; 64*conc + v] in LDS.
// Phase 2: y = mask_s/2 * (u @ Ws + 65*bs), Ws streamed from L2.
__global__ __launch_bounds__(256) void kFused(
    const float* __restrict__ stu,
    const float* __restrict__ conc,
    const float* __restrict__ nbr,
    const float* __restrict__ Ws,
    const float* __restrict__ bs,
    const float* __restrict__ Ww,
    float* __restrict__ y)
{
    const int t  = threadIdx.x;
    const int b0 = blockIdx.x * G;

    __shared__ float logits[NN];
    __shared__ float wsm[NN];
    __shared__ float sred[2][2];                      // [wave][0]=conc, [1]=stu
    __shared__ float maskh[G];
    __shared__ __align__(16) float u[G][2 * DD];      // 4 KB
    __shared__ __align__(16) float scratch[8 * G * DD]; // 16 KB (phase1 uses first 8*DD)

    const int cg = t & 31;   // float4 column group within a 128-wide row
    const int g8 = t >> 5;   // row group 0..7
    const float4 wb = reinterpret_cast<const float4*>(Ww + DD)[cg];  // Ww_b slice

    for (int g = 0; g < G; ++g) {
        const int b = b0 + g;
        const float4* nb4 = reinterpret_cast<const float4*>(nbr + (size_t)b * NN * DD);

        // ---- load neighbor tile into registers (rows g8+8i, cols cg*4..+3) ----
        float4 val[8];
#pragma unroll
        for (int i = 0; i < 8; ++i) val[i] = nb4[t + 256 * i];

        // ---- logits: per-row dot with Ww_b, reduced within each 32-lane group ----
#pragma unroll
        for (int i = 0; i < 8; ++i) {
            float x = val[i].x * wb.x + val[i].y * wb.y + val[i].z * wb.z + val[i].w * wb.w;
            x += __shfl_xor(x, 1);
            x += __shfl_xor(x, 2);
            x += __shfl_xor(x, 4);
            x += __shfl_xor(x, 8);
            x += __shfl_xor(x, 16);
            if (cg == 0) logits[g8 + 8 * i] = x;
        }

        // ---- stu/conc rows -> u staging + row sums for masks ----
        if (t < DD) {
            float cs = conc[(size_t)b * DD + t];
            float ss = stu [(size_t)b * DD + t];
            u[g][t]      = 65.0f * ss;
            u[g][DD + t] = 64.0f * cs;      // + v added after reduce (same thread)
            float c2 = cs, s2 = ss;
            c2 += __shfl_xor(c2, 1);  s2 += __shfl_xor(s2, 1);
            c2 += __shfl_xor(c2, 2);  s2 += __shfl_xor(s2, 2);
            c2 += __shfl_xor(c2, 4);  s2 += __shfl_xor(s2, 4);
            c2 += __shfl_xor(c2, 8);  s2 += __shfl_xor(s2, 8);
            c2 += __shfl_xor(c2, 16); s2 += __shfl_xor(s2, 16);
            c2 += __shfl_xor(c2, 32); s2 += __shfl_xor(s2, 32);
            if ((t & 63) == 0) { sred[t >> 6][0] = c2; sred[t >> 6][1] = s2; }
        }
        __syncthreads();

        // ---- softmax over 64 logits (wave 0) ----
        if (t < NN) {
            float csum = sred[0][0] + sred[1][0];
            float l = logits[t];
            float m = l;
            m = fmaxf(m, __shfl_xor(m, 1));
            m = fmaxf(m, __shfl_xor(m, 2));
            m = fmaxf(m, __shfl_xor(m, 4));
            m = fmaxf(m, __shfl_xor(m, 8));
            m = fmaxf(m, __shfl_xor(m, 16));
            m = fmaxf(m, __shfl_xor(m, 32));
            float e = __expf(l - m);
            float s = e;
            s += __shfl_xor(s, 1);
            s += __shfl_xor(s, 2);
            s += __shfl_xor(s, 4);
            s += __shfl_xor(s, 8);
            s += __shfl_xor(s, 16);
            s += __shfl_xor(s, 32);
            wsm[t] = (csum != 0.0f) ? (e / s) : (1.0f / 64.0f);
        }
        if (t == 0) maskh[g] = ((sred[0][1] + sred[1][1]) != 0.0f) ? 0.5f : 0.0f;
        __syncthreads();

        // ---- weighted sum over rows, in registers ----
        float4 a = {0.f, 0.f, 0.f, 0.f};
#pragma unroll
        for (int i = 0; i < 8; ++i) {
            float w = wsm[g8 + 8 * i];     // broadcast within half-wave
            a.x += w * val[i].x; a.y += w * val[i].y;
            a.z += w * val[i].z; a.w += w * val[i].w;
        }
        reinterpret_cast<float4*>(scratch)[g8 * 32 + cg] = a;  // part[g8][cg]
        __syncthreads();

        if (t < DD) {
            float s = 0.0f;
#pragma unroll
            for (int k = 0; k < 8; ++k) s += scratch[k * DD + t];
            u[g][DD + t] += s;             // same thread that wrote 64*cs
        }
        __syncthreads();                   // part/logits free; u[g] complete
    }

    // ---- phase 2: y[b0+r][:] = maskh[r] * (u[r] @ Ws + 65*bs) ----
    const int kg = t >> 5;                 // k-group 0..7 (k in [kg*32, kg*32+32))
    float4 acc0 = {0,0,0,0}, acc1 = {0,0,0,0}, acc2 = {0,0,0,0}, acc3 = {0,0,0,0};
    const float4* Ws4 = reinterpret_cast<const float4*>(Ws);   // 256 x 32 float4
#pragma unroll 4
    for (int j = 0; j < 32; ++j) {
        const int k = kg * 32 + j;
        float4 wv = Ws4[k * 32 + cg];      // coalesced, L2-resident
        float u0 = u[0][k], u1 = u[1][k], u2 = u[2][k], u3 = u[3][k];
        acc0.x += u0 * wv.x; acc0.y += u0 * wv.y; acc0.z += u0 * wv.z; acc0.w += u0 * wv.w;
        acc1.x += u1 * wv.x; acc1.y += u1 * wv.y; acc1.z += u1 * wv.z; acc1.w += u1 * wv.w;
        acc2.x += u2 * wv.x; acc2.y += u2 * wv.y; acc2.z += u2 * wv.z; acc2.w += u2 * wv.w;
        acc3.x += u3 * wv.x; acc3.y += u3 * wv.y; acc3.z += u3 * wv.z; acc3.w += u3 * wv.w;
    }
    {
        float4* pr = reinterpret_cast<float4*>(scratch);       // pr[kg][r][32 float4]
        pr[(kg * G + 0) * 32 + cg] = acc0;
        pr[(kg * G + 1) * 32 + cg] = acc1;
        pr[(kg * G + 2) * 32 + cg] = acc2;
        pr[(kg * G + 3) * 32 + cg] = acc3;
    }
    __syncthreads();
#pragma unroll
    for (int i = 0; i < 2; ++i) {
        const int idx = t + 256 * i;       // 0..511
        const int r = idx >> 7;
        const int c = idx & 127;
        float s = 0.0f;
#pragma unroll
        for (int k2 = 0; k2 < 8; ++k2) s += scratch[(k2 * G + r) * DD + c];
        y[(size_t)(b0 + r) * DD + c] = (s + 65.0f * bs[c]) * maskh[r];
    }
}

extern "C" void kernel_launch(void* const* d_in, const int* in_sizes, int n_in,
                              void* d_out, int out_size, void* d_ws, size_t ws_size,
                              hipStream_t stream) {
    const float* stu  = (const float*)d_in[0];
    const float* conc = (const float*)d_in[1];
    const float* nbr  = (const float*)d_in[2];
    const float* Ws   = (const float*)d_in[3];
    const float* bs   = (const float*)d_in[4];
    const float* Ww   = (const float*)d_in[5];
    float* y = (float*)d_out;

    kFused<<<BB / G, 256, 0, stream>>>(stu, conc, nbr, Ws, bs, Ww, y);
}